// Round 2
// baseline (718.572 us; speedup 1.0000x reference)
//
#include <hip/hip_runtime.h>
#include <math.h>

// Problem constants: B=16, S=256 -> N=4096 tokens; D=256; U=2000.
#define N_TOK 4096
#define DIM   256
#define NURL  2000
#define TCH   8     // tokens processed per pass over trans[u]

// Workspace layout (int32 entries; total 10240 ints = 40 KB):
#define WS_COUNTS 0      // [2000]  tokens per url
#define WS_OFFS   2048   // [2000]  exclusive prefix (bucket start per url)
#define WS_CURS   4096   // [2000]  scatter cursor (init = offs)
#define WS_BUCKET 6144   // [4096]  token ids grouped by url

// ---------------- pass 1: zero counts ----------------
__global__ __launch_bounds__(256) void zero_k(int* __restrict__ ws) {
    const int i = blockIdx.x * 256 + threadIdx.x;
    if (i < NURL) ws[WS_COUNTS + i] = 0;
}

// ---------------- pass 2: histogram ----------------
__global__ __launch_bounds__(256) void hist_k(const int* __restrict__ urls,
                                              int* __restrict__ ws) {
    const int n = blockIdx.x * 256 + threadIdx.x;   // grid covers exactly N_TOK
    atomicAdd(&ws[WS_COUNTS + urls[n]], 1);
}

// ---------------- pass 3: exclusive scan (1 wave; lane handles 32 urls) ----
__global__ __launch_bounds__(64) void scan_k(int* __restrict__ ws) {
    const int lane = threadIdx.x;
    const int base = lane * 32;                      // 64*32 = 2048 >= 2000
    int c[32];
    int local = 0;
#pragma unroll
    for (int i = 0; i < 32; ++i) {
        const int u = base + i;
        c[i] = (u < NURL) ? ws[WS_COUNTS + u] : 0;
        local += c[i];
    }
    int x = local;
    for (int off = 1; off < 64; off <<= 1) {
        const int y = __shfl_up(x, off);
        if (lane >= off) x += y;
    }
    int run = x - local;
#pragma unroll
    for (int i = 0; i < 32; ++i) {
        const int u = base + i;
        if (u < NURL) { ws[WS_OFFS + u] = run; ws[WS_CURS + u] = run; }
        run += c[i];
    }
}

// ---------------- pass 4: scatter token ids into url buckets ----------------
__global__ __launch_bounds__(256) void scatter_k(const int* __restrict__ urls,
                                                 int* __restrict__ ws) {
    const int n = blockIdx.x * 256 + threadIdx.x;
    const int u = urls[n];
    const int pos = atomicAdd(&ws[WS_CURS + u], 1);
    ws[WS_BUCKET + pos] = n;
}

// ---------------- pass 5: compute ----------------
// Two urls per 256-thread block. Waves {0,1} -> url A, waves {2,3} -> url B.
// Within a url, wave `half` streams rows [128*half, 128*half+127] of trans[u]
// exactly like the original per-token streamer (1 float4/lane/row, unroll 8),
// but shares every row load across up to TCH=8 tokens (64 FLOP per 16 B).
// Partials for the 4 tokens the *other* wave finalizes go through LDS once.
#define FMA4(acc, xv, tv)                 \
    acc.x = fmaf((xv), (tv).x, acc.x);    \
    acc.y = fmaf((xv), (tv).y, acc.y);    \
    acc.z = fmaf((xv), (tv).z, acc.z);    \
    acc.w = fmaf((xv), (tv).w, acc.w);

__global__ __launch_bounds__(256) void compute_k(
    const float* __restrict__ inp,    // [N, D]
    const float* __restrict__ trans,  // [U, D, D]  (d_in, d_out)
    const float* __restrict__ bias,   // [U, D]
    const int*   __restrict__ ws,
    float*       __restrict__ out)    // [N, D]
{
    const int tid  = threadIdx.x;
    const int wave = tid >> 6;
    const int lane = tid & 63;
    const int wq   = wave >> 1;   // url slot within block (0/1)
    const int half = wave & 1;    // row-half within url (0/1)

    const int cntA = ws[WS_COUNTS + 2 * blockIdx.x + 0];
    const int cntB = ws[WS_COUNTS + 2 * blockIdx.x + 1];
    const int nch  = max((cntA + TCH - 1) / TCH, (cntB + TCH - 1) / TCH);
    if (nch == 0) return;         // uniform across block

    const int u     = 2 * blockIdx.x + wq;
    const int cnt   = (wq == 0) ? cntA : cntB;
    const int start = ws[WS_OFFS + u];

    __shared__ __align__(16) float xs[2][TCH][DIM];    // 16 KB
    __shared__ __align__(16) float part[2][TCH][DIM];  // 16 KB
    __shared__ int toks[2][TCH];

    const float4 bv = reinterpret_cast<const float4*>(bias + (size_t)u * DIM)[lane];
    const float4* T4 =
        reinterpret_cast<const float4*>(trans + (size_t)u * DIM * DIM) + lane;
    const int dbase = half * 128;

    for (int c = 0; c < nch; ++c) {
        const int nk = min(TCH, cnt - c * TCH);   // <=0 when this url is done

        // stage x rows: wave stages tokens [half*4, half*4+3] of its url
#pragma unroll
        for (int k = 0; k < 4; ++k) {
            const int kk = half * 4 + k;
            if (kk < nk) {
                const int tok = ws[WS_BUCKET + start + c * TCH + kk];
                reinterpret_cast<float4*>(xs[wq][kk])[lane] =
                    reinterpret_cast<const float4*>(inp + (size_t)tok * DIM)[lane];
                if (lane == 0) toks[wq][kk] = tok;
            }
        }
        __syncthreads();

        float4 a0 = {0,0,0,0}, a1 = {0,0,0,0}, a2 = {0,0,0,0}, a3 = {0,0,0,0};
        float4 a4 = {0,0,0,0}, a5 = {0,0,0,0}, a6 = {0,0,0,0}, a7 = {0,0,0,0};

        if (nk > 0) {
            const float* xw = &xs[wq][0][0];      // [TCH][DIM]
#pragma unroll 8
            for (int d0 = 0; d0 < 128; ++d0) {
                const int d = dbase + d0;
                const float4 tv = T4[(size_t)d * (DIM / 4)];
                const float x0 = xw[0 * DIM + d];
                const float x1 = xw[1 * DIM + d];
                const float x2 = xw[2 * DIM + d];
                const float x3 = xw[3 * DIM + d];
                const float x4 = xw[4 * DIM + d];
                const float x5 = xw[5 * DIM + d];
                const float x6 = xw[6 * DIM + d];
                const float x7 = xw[7 * DIM + d];
                FMA4(a0, x0, tv) FMA4(a1, x1, tv) FMA4(a2, x2, tv) FMA4(a3, x3, tv)
                FMA4(a4, x4, tv) FMA4(a5, x5, tv) FMA4(a6, x6, tv) FMA4(a7, x7, tv)
            }

            // hand the other wave the 4 tokens it finalizes (compile-time indices)
            if (half == 0) {
                reinterpret_cast<float4*>(part[wq][4])[lane] = a4;
                reinterpret_cast<float4*>(part[wq][5])[lane] = a5;
                reinterpret_cast<float4*>(part[wq][6])[lane] = a6;
                reinterpret_cast<float4*>(part[wq][7])[lane] = a7;
            } else {
                reinterpret_cast<float4*>(part[wq][0])[lane] = a0;
                reinterpret_cast<float4*>(part[wq][1])[lane] = a1;
                reinterpret_cast<float4*>(part[wq][2])[lane] = a2;
                reinterpret_cast<float4*>(part[wq][3])[lane] = a3;
            }
        }
        __syncthreads();

        if (nk > 0) {
            if (half == 0) {
                // finalize tokens 0..3: own acc (rows 0-127) + partner partial
#define FIN(K, ACC)                                                            \
                if ((K) < nk) {                                                \
                    const float4 p =                                           \
                        reinterpret_cast<const float4*>(part[wq][K])[lane];    \
                    float4 o;                                                  \
                    o.x = tanhf(ACC.x + p.x + bv.x);                           \
                    o.y = tanhf(ACC.y + p.y + bv.y);                           \
                    o.z = tanhf(ACC.z + p.z + bv.z);                           \
                    o.w = tanhf(ACC.w + p.w + bv.w);                           \
                    reinterpret_cast<float4*>(                                 \
                        out + (size_t)toks[wq][K] * DIM)[lane] = o;            \
                }
                FIN(0, a0) FIN(1, a1) FIN(2, a2) FIN(3, a3)
            } else {
                FIN(4, a4) FIN(5, a5) FIN(6, a6) FIN(7, a7)
#undef FIN
            }
        }
        __syncthreads();   // protect xs/part before next chunk's staging
    }
}

extern "C" void kernel_launch(void* const* d_in, const int* in_sizes, int n_in,
                              void* d_out, int out_size, void* d_ws, size_t ws_size,
                              hipStream_t stream) {
    const float* inp   = (const float*)d_in[0];  // [B,S,D] f32
    const int*   urls  = (const int*)  d_in[1];  // [B,S]   i32
    const float* trans = (const float*)d_in[2];  // [U,D,D] f32
    const float* bias  = (const float*)d_in[3];  // [U,D]   f32
    float*       out   = (float*)d_out;
    int*         ws    = (int*)d_ws;             // needs 40 KB

    zero_k<<<(NURL + 255) / 256, 256, 0, stream>>>(ws);
    hist_k<<<N_TOK / 256, 256, 0, stream>>>(urls, ws);
    scan_k<<<1, 64, 0, stream>>>(ws);
    scatter_k<<<N_TOK / 256, 256, 0, stream>>>(urls, ws);
    compute_k<<<NURL / 2, 256, 0, stream>>>(inp, trans, bias, ws, out);
}

// Round 3
// 674.016 us; speedup vs baseline: 1.0661x; 1.0661x over previous
//
#include <hip/hip_runtime.h>
#include <math.h>

// Problem constants: B=16, S=256 -> N=4096 tokens; D=256; U=2000.
#define N_TOK 4096
#define DIM   256
#define NURL  2000

// Workspace layout (int32 entries; total 10240 ints = 40 KB):
#define WS_COUNTS 0      // [2000]  tokens per url
#define WS_OFFS   2048   // [2000]  exclusive prefix (bucket start per url)
#define WS_CURS   4096   // [2000]  scatter cursor (init = offs)
#define WS_BUCKET 6144   // [4096]  token ids grouped (sorted) by url

// ---------------- pass 1: zero counts ----------------
__global__ __launch_bounds__(256) void zero_k(int* __restrict__ ws) {
    const int i = blockIdx.x * 256 + threadIdx.x;
    if (i < NURL) ws[WS_COUNTS + i] = 0;
}

// ---------------- pass 2: histogram ----------------
__global__ __launch_bounds__(256) void hist_k(const int* __restrict__ urls,
                                              int* __restrict__ ws) {
    const int n = blockIdx.x * 256 + threadIdx.x;   // grid covers exactly N_TOK
    atomicAdd(&ws[WS_COUNTS + urls[n]], 1);
}

// ---------------- pass 3: exclusive scan (1 wave; lane handles 32 urls) ----
__global__ __launch_bounds__(64) void scan_k(int* __restrict__ ws) {
    const int lane = threadIdx.x;
    const int base = lane * 32;                      // 64*32 = 2048 >= 2000
    int c[32];
    int local = 0;
#pragma unroll
    for (int i = 0; i < 32; ++i) {
        const int u = base + i;
        c[i] = (u < NURL) ? ws[WS_COUNTS + u] : 0;
        local += c[i];
    }
    int x = local;
    for (int off = 1; off < 64; off <<= 1) {
        const int y = __shfl_up(x, off);
        if (lane >= off) x += y;
    }
    int run = x - local;
#pragma unroll
    for (int i = 0; i < 32; ++i) {
        const int u = base + i;
        if (u < NURL) { ws[WS_OFFS + u] = run; ws[WS_CURS + u] = run; }
        run += c[i];
    }
}

// ---------------- pass 4: scatter token ids into url buckets ----------------
__global__ __launch_bounds__(256) void scatter_k(const int* __restrict__ urls,
                                                 int* __restrict__ ws) {
    const int n = blockIdx.x * 256 + threadIdx.x;
    const int u = urls[n];
    const int pos = atomicAdd(&ws[WS_CURS + u], 1);
    ws[WS_BUCKET + pos] = n;
}

// ---------------- pass 5: compute ----------------
// The proven per-token streamer (1 wave / token, 1 KB coalesced row loads,
// unroll 8, no inter-wave barriers, ~32 waves/CU), but blocks walk the
// url-sorted bucket order with an XCD-contiguous swizzle: consecutive
// bucket positions (usually the same url) land on the SAME XCD, so repeat
// reads of trans[u] hit that XCD's 4 MB L2 instead of HBM.
__global__ __launch_bounds__(64) void compute_tok(
    const float* __restrict__ inp,    // [N, D]
    const int*   __restrict__ urls,   // [N]
    const float* __restrict__ trans,  // [U, D, D]  (d_in, d_out)
    const float* __restrict__ bias,   // [U, D]
    const int*   __restrict__ ws,
    float*       __restrict__ out)    // [N, D]
{
    const int b    = blockIdx.x;
    // HW maps block b -> XCD (b % 8). Give XCD k the contiguous bucket
    // range [k*512, (k+1)*512): work = (b%8)*512 + b/8. Bijective (4096%8==0).
    const int work = ((b & 7) << 9) | (b >> 3);
    const int n    = ws[WS_BUCKET + work];
    const int t    = threadIdx.x;   // 0..63
    const int u    = urls[n];

    __shared__ float xs[DIM];
    reinterpret_cast<float4*>(xs)[t] =
        reinterpret_cast<const float4*>(inp + (size_t)n * DIM)[t];
    __syncthreads();

    const float4* T4 = reinterpret_cast<const float4*>(
                           trans + (size_t)u * DIM * DIM) + t;
    float4 acc = reinterpret_cast<const float4*>(bias + (size_t)u * DIM)[t];

#pragma unroll 8
    for (int d = 0; d < DIM; ++d) {
        const float  x  = xs[d];
        const float4 tv = T4[(size_t)d * (DIM / 4)];
        acc.x = fmaf(x, tv.x, acc.x);
        acc.y = fmaf(x, tv.y, acc.y);
        acc.z = fmaf(x, tv.z, acc.z);
        acc.w = fmaf(x, tv.w, acc.w);
    }

    float4 o;
    o.x = tanhf(acc.x);
    o.y = tanhf(acc.y);
    o.z = tanhf(acc.z);
    o.w = tanhf(acc.w);
    reinterpret_cast<float4*>(out + (size_t)n * DIM)[t] = o;
}

extern "C" void kernel_launch(void* const* d_in, const int* in_sizes, int n_in,
                              void* d_out, int out_size, void* d_ws, size_t ws_size,
                              hipStream_t stream) {
    const float* inp   = (const float*)d_in[0];  // [B,S,D] f32
    const int*   urls  = (const int*)  d_in[1];  // [B,S]   i32
    const float* trans = (const float*)d_in[2];  // [U,D,D] f32
    const float* bias  = (const float*)d_in[3];  // [U,D]   f32
    float*       out   = (float*)d_out;
    int*         ws    = (int*)d_ws;             // needs 40 KB

    zero_k<<<(NURL + 255) / 256, 256, 0, stream>>>(ws);
    hist_k<<<N_TOK / 256, 256, 0, stream>>>(urls, ws);
    scan_k<<<1, 64, 0, stream>>>(ws);
    scatter_k<<<N_TOK / 256, 256, 0, stream>>>(urls, ws);
    compute_tok<<<N_TOK, 64, 0, stream>>>(inp, urls, trans, bias, ws, out);
}